// Round 5
// baseline (341.860 us; speedup 1.0000x reference)
//
#include <hip/hip_runtime.h>
#include <stdint.h>

typedef unsigned short U16;
typedef unsigned int   U32;
typedef __attribute__((ext_vector_type(8))) short short8;   // 8 bf16 = 4 VGPRs (MFMA A/B frag)
typedef __attribute__((ext_vector_type(4))) float floatx4;  // MFMA C/D frag

#define HW 3136   // 56*56

__device__ __forceinline__ U16 f2b(float f){
    union { float f; unsigned int i; } v; v.f = f;
    unsigned int u = (v.i + 0x7FFFu + ((v.i >> 16) & 1u)) >> 16;  // RNE
    return (U16)u;
}
// load 8 consecutive fp32, round to bf16, return as MFMA 8x-bf16 fragment
__device__ __forceinline__ short8 pack8(const float* p){
    float4 a = *reinterpret_cast<const float4*>(p);
    float4 b = *reinterpret_cast<const float4*>(p + 4);
    short8 r;
    r[0]=(short)f2b(a.x); r[1]=(short)f2b(a.y); r[2]=(short)f2b(a.z); r[3]=(short)f2b(a.w);
    r[4]=(short)f2b(b.x); r[5]=(short)f2b(b.y); r[6]=(short)f2b(b.z); r[7]=(short)f2b(b.w);
    return r;
}

// ---------------------------------------------------------------------------
// k_pre: fold BN into fp32 scale/shift; transpose+convert w2 (fp32) ->
// bf16 [g][tap][oc 32][ic 32].
// bn layout (fp32): [0:128) s1 [128:256) sh1 [256:384) s2 [384:512) sh2
//                   [512:1024) s3 [1024:1536) sh3
// ---------------------------------------------------------------------------
__global__ void k_pre(const float* __restrict__ w2,
                      const float* g1, const float* b1, const float* m1, const float* v1,
                      const float* g2, const float* b2, const float* m2, const float* v2,
                      const float* g3, const float* b3, const float* m3, const float* v3,
                      U16* __restrict__ w2t, float* __restrict__ bn){
  int i = blockIdx.x * 256 + threadIdx.x;
  if (i < 4*9*32*32) {
    int ic  = i & 31;
    int oc  = (i >> 5) & 31;
    int gt  = i >> 10;          // g*9 + tap
    int g_  = gt / 9, tap = gt % 9;
    w2t[i] = f2b(w2[((g_*32 + oc)*32 + ic)*9 + tap]);
  } else {
    int j = i - 4*9*32*32;
    if (j >= 768) return;
    const float *gp, *bp, *mp, *vp; int c, so, sho;
    if (j < 128)      { c = j;       gp=g1; bp=b1; mp=m1; vp=v1; so = 0;   sho = 128;  }
    else if (j < 256) { c = j - 128; gp=g2; bp=b2; mp=m2; vp=v2; so = 256; sho = 384;  }
    else              { c = j - 256; gp=g3; bp=b3; mp=m3; vp=v3; so = 512; sho = 1024; }
    float s = gp[c] / sqrtf(vp[c] + 1e-5f);
    bn[so + c]  = s;
    bn[sho + c] = bp[c] - mp[c] * s;
  }
}

// ---------------------------------------------------------------------------
// k_conv1: t1 = mask * relu(bn1(mask * conv1x1_g(x)))   (512 -> 128, G=4)
// one wave per (b, g, 8x8 cell). x fp32 -> bf16 staged px-major [ic][64] LDS.
// ---------------------------------------------------------------------------
__global__ __launch_bounds__(64) void k_conv1(const float* __restrict__ x,
        const float* __restrict__ mask, const float* __restrict__ w1,
        const float* __restrict__ bn, U16* __restrict__ t1){
  const int lane = threadIdx.x;
  const int b = blockIdx.z, g = blockIdx.y;
  const int mh = blockIdx.x / 7, mw = blockIdx.x % 7;
  const int h0 = mh*8, w0 = mw*8;
  const float m = mask[((b*4 + g)*7 + mh)*7 + mw];
  U16* t1g = t1 + (size_t)(b*128 + g*32) * HW;
  if (m == 0.0f){
    const int off = (h0 + (lane >> 3))*56 + w0 + (lane & 7);
    #pragma unroll
    for (int oc = 0; oc < 32; ++oc) t1g[oc*HW + off] = 0;  // conv2 halo reads these
    return;
  }
  __shared__ __align__(16) U16 xs[128*64];                 // [ic][px] bf16
  const float* xg = x + (size_t)(b*512 + g*128) * HW;
  const int r_ = lane & 7, icl = lane >> 3;
  #pragma unroll
  for (int p = 0; p < 16; ++p){
    int ic = p*8 + icl;
    const float* src = xg + ic*HW + (h0 + r_)*56 + w0;
    float4 v0 = *reinterpret_cast<const float4*>(src);
    float4 v1 = *reinterpret_cast<const float4*>(src + 4);
    uint4 pk;
    pk.x = (U32)f2b(v0.x) | ((U32)f2b(v0.y) << 16);
    pk.y = (U32)f2b(v0.z) | ((U32)f2b(v0.w) << 16);
    pk.z = (U32)f2b(v1.x) | ((U32)f2b(v1.y) << 16);
    pk.w = (U32)f2b(v1.z) | ((U32)f2b(v1.w) << 16);
    *reinterpret_cast<uint4*>(&xs[ic*64 + r_*8]) = pk;
  }
  __syncthreads();
  const int quad = lane >> 4, l15 = lane & 15;
  const float* wg = w1 + (g*32)*128;                       // fp32 [oc 0..31][ic 0..127]
  short8 afr[2][4];
  #pragma unroll
  for (int oct = 0; oct < 2; ++oct)
    #pragma unroll
    for (int ks = 0; ks < 4; ++ks)
      afr[oct][ks] = pack8(wg + (oct*16 + l15)*128 + ks*32 + quad*8);
  floatx4 acc[2][4] = {};
  #pragma unroll
  for (int pxt = 0; pxt < 4; ++pxt){
    short8 bfr[4];
    #pragma unroll
    for (int ks = 0; ks < 4; ++ks)
      #pragma unroll
      for (int j = 0; j < 8; ++j)
        bfr[ks][j] = (short)xs[(ks*32 + quad*8 + j)*64 + pxt*16 + l15];
    #pragma unroll
    for (int ks = 0; ks < 4; ++ks){
      acc[0][pxt] = __builtin_amdgcn_mfma_f32_16x16x32_bf16(afr[0][ks], bfr[ks], acc[0][pxt], 0,0,0);
      acc[1][pxt] = __builtin_amdgcn_mfma_f32_16x16x32_bf16(afr[1][ks], bfr[ks], acc[1][pxt], 0,0,0);
    }
  }
  #pragma unroll
  for (int oct = 0; oct < 2; ++oct)
    #pragma unroll
    for (int reg = 0; reg < 4; ++reg){
      int oc = oct*16 + quad*4 + reg;
      float sc = bn[g*32 + oc], sh = bn[128 + g*32 + oc];
      #pragma unroll
      for (int pxt = 0; pxt < 4; ++pxt){
        int px = pxt*16 + l15;
        float y = fmaxf(sc * (m * acc[oct][pxt][reg]) + sh, 0.0f) * m;
        t1g[oc*HW + (h0 + (px>>3))*56 + w0 + (px & 7)] = f2b(y);
      }
    }
}

// ---------------------------------------------------------------------------
// k_conv2: t2 = mask * relu(bn2(conv3x3_g(t1)))   (128 -> 128, G=4, pad 1)
// 9 accumulating K=32 MFMAs over a 10x10 haloed LDS tile. m==0: t2 never read.
// ---------------------------------------------------------------------------
__global__ __launch_bounds__(64) void k_conv2(const U16* __restrict__ t1,
        const float* __restrict__ mask, const U16* __restrict__ w2t,
        const float* __restrict__ bn, U16* __restrict__ t2){
  const int lane = threadIdx.x;
  const int b = blockIdx.z, g = blockIdx.y;
  const int mh = blockIdx.x / 7, mw = blockIdx.x % 7;
  const float m = mask[((b*4 + g)*7 + mh)*7 + mw];
  if (m == 0.0f) return;
  const int h0 = mh*8, w0 = mw*8;
  __shared__ __align__(16) U16 s[32*100];                  // [ic][10r][10c], halo 1
  const U16* tg = t1 + (size_t)(b*128 + g*32) * HW;
  #pragma unroll 2
  for (int p = 0; p < 50; ++p){
    int e = p*64 + lane;                                   // e < 3200
    int ic = e / 100, rem = e % 100;
    int lr = rem / 10, lc = rem % 10;
    int hh = h0 - 1 + lr, ww = w0 - 1 + lc;
    U16 v = 0;
    if (hh >= 0 && hh < 56 && ww >= 0 && ww < 56) v = tg[ic*HW + hh*56 + ww];
    s[e] = v;
  }
  __syncthreads();
  const int quad = lane >> 4, l15 = lane & 15;
  const U16* wg = w2t + g*9*32*32;                         // bf16 [tap][oc][ic]
  floatx4 acc[2][4] = {};
  #pragma unroll
  for (int kh = 0; kh < 3; ++kh)
    #pragma unroll
    for (int kw = 0; kw < 3; ++kw){
      int tap = kh*3 + kw;
      short8 a0 = *reinterpret_cast<const short8*>(wg + (tap*32 +      l15)*32 + quad*8);
      short8 a1 = *reinterpret_cast<const short8*>(wg + (tap*32 + 16 + l15)*32 + quad*8);
      #pragma unroll
      for (int pxt = 0; pxt < 4; ++pxt){
        int lr = pxt*2 + (l15 >> 3) + kh, lc = (l15 & 7) + kw;
        short8 bfr;
        #pragma unroll
        for (int j = 0; j < 8; ++j)
          bfr[j] = (short)s[(quad*8 + j)*100 + lr*10 + lc];
        acc[0][pxt] = __builtin_amdgcn_mfma_f32_16x16x32_bf16(a0, bfr, acc[0][pxt], 0,0,0);
        acc[1][pxt] = __builtin_amdgcn_mfma_f32_16x16x32_bf16(a1, bfr, acc[1][pxt], 0,0,0);
      }
    }
  U16* og = t2 + (size_t)(b*128 + g*32) * HW;
  #pragma unroll
  for (int oct = 0; oct < 2; ++oct)
    #pragma unroll
    for (int reg = 0; reg < 4; ++reg){
      int oc = oct*16 + quad*4 + reg;
      float sc = bn[256 + g*32 + oc], sh = bn[384 + g*32 + oc];
      #pragma unroll
      for (int pxt = 0; pxt < 4; ++pxt){
        int pr = pxt*2 + (l15 >> 3), pc = l15 & 7;
        float y = fmaxf(sc * acc[oct][pxt][reg] + sh, 0.0f) * m;
        og[oc*HW + (h0 + pr)*56 + w0 + pc] = f2b(y);
      }
    }
}

// ---------------------------------------------------------------------------
// k_conv3: out = relu(bn3(conv1x1_g(t2)) + x)   (128 -> 512, G=4)
// OUTPUT IS FP32 (reference dtype). residual x in fp32.
// m==0: conv3(0)=0 -> out = relu(x + sh3), no t2 read.
// ---------------------------------------------------------------------------
__global__ __launch_bounds__(64) void k_conv3(const U16* __restrict__ t2,
        const float* __restrict__ x, const float* __restrict__ mask,
        const float* __restrict__ w3, const float* __restrict__ bn,
        float* __restrict__ out){
  const int lane = threadIdx.x;
  const int b = blockIdx.z, g = blockIdx.y;
  const int mh = blockIdx.x / 7, mw = blockIdx.x % 7;
  const int h0 = mh*8, w0 = mw*8;
  const float m = mask[((b*4 + g)*7 + mh)*7 + mw];
  const float* xg = x + (size_t)(b*512 + g*128) * HW;
  float* og = out + (size_t)(b*512 + g*128) * HW;
  if (m == 0.0f){
    const int off = (h0 + (lane >> 3))*56 + w0 + (lane & 7);
    #pragma unroll 8
    for (int oc = 0; oc < 128; ++oc){
      og[oc*HW + off] = fmaxf(xg[oc*HW + off] + bn[1024 + g*128 + oc], 0.0f);
    }
    return;
  }
  __shared__ __align__(16) U16 xs[32*64];                  // t2 cell, [ic][px] bf16
  const U16* tg = t2 + (size_t)(b*128 + g*32) * HW;
  {
    const int r_ = lane & 7, icl = lane >> 3;
    #pragma unroll
    for (int p = 0; p < 4; ++p){
      int ic = p*8 + icl;
      const uint4 v = *reinterpret_cast<const uint4*>(tg + ic*HW + (h0 + r_)*56 + w0);
      *reinterpret_cast<uint4*>(&xs[ic*64 + r_*8]) = v;
    }
  }
  __syncthreads();
  const int quad = lane >> 4, l15 = lane & 15;
  short8 bfr[4];
  #pragma unroll
  for (int pxt = 0; pxt < 4; ++pxt)
    #pragma unroll
    for (int j = 0; j < 8; ++j)
      bfr[pxt][j] = (short)xs[(quad*8 + j)*64 + pxt*16 + l15];
  #pragma unroll
  for (int oct = 0; oct < 8; ++oct){
    short8 afr = pack8(w3 + (size_t)(g*128 + oct*16 + l15)*32 + quad*8);  // fp32 [oc][ic32]
    floatx4 acc[4] = {};
    #pragma unroll
    for (int pxt = 0; pxt < 4; ++pxt)
      acc[pxt] = __builtin_amdgcn_mfma_f32_16x16x32_bf16(afr, bfr[pxt], acc[pxt], 0,0,0);
    #pragma unroll
    for (int reg = 0; reg < 4; ++reg){
      int oc = oct*16 + quad*4 + reg;
      float sc = bn[512 + g*128 + oc], sh = bn[1024 + g*128 + oc];
      #pragma unroll
      for (int pxt = 0; pxt < 4; ++pxt){
        int pr = pxt*2 + (l15 >> 3), pc = l15 & 7;
        int o2 = oc*HW + (h0 + pr)*56 + w0 + pc;
        og[o2] = fmaxf(sc * acc[pxt][reg] + sh + xg[o2], 0.0f);
      }
    }
  }
}

// ---------------------------------------------------------------------------
extern "C" void kernel_launch(void* const* d_in, const int* in_sizes, int n_in,
                              void* d_out, int out_size, void* d_ws, size_t ws_size,
                              hipStream_t stream){
  const float* x    = (const float*)d_in[0];
  const float* mask = (const float*)d_in[1];
  const float* w1   = (const float*)d_in[2];
  const float* g1   = (const float*)d_in[3];
  const float* b1   = (const float*)d_in[4];
  const float* m1   = (const float*)d_in[5];
  const float* v1   = (const float*)d_in[6];
  const float* w2   = (const float*)d_in[7];
  const float* g2   = (const float*)d_in[8];
  const float* b2   = (const float*)d_in[9];
  const float* m2   = (const float*)d_in[10];
  const float* v2   = (const float*)d_in[11];
  const float* w3   = (const float*)d_in[12];
  const float* g3   = (const float*)d_in[13];
  const float* b3   = (const float*)d_in[14];
  const float* m3   = (const float*)d_in[15];
  const float* v3   = (const float*)d_in[16];

  char* ws = (char*)d_ws;
  U16*   w2t = (U16*)ws;                               //      0 .. 73,728
  float* bn  = (float*)(ws + 73728);                   // 73,728 .. 79,872
  U16*   t1  = (U16*)(ws + 79872);                     // 12,845,056 B
  U16*   t2  = (U16*)(ws + 79872 + 12845056);          // 12,845,056 B (total ~24.6 MB)

  k_pre<<<147, 256, 0, stream>>>(w2, g1,b1,m1,v1, g2,b2,m2,v2, g3,b3,m3,v3, w2t, bn);
  dim3 grid(49, 4, 16);   // (mh*7+mw, group, batch)
  k_conv1<<<grid, 64, 0, stream>>>(x, mask, w1, bn, t1);
  k_conv2<<<grid, 64, 0, stream>>>(t1, mask, w2t, bn, t2);
  k_conv3<<<grid, 64, 0, stream>>>(t2, x, mask, w3, bn, (float*)d_out);
}